// Round 5
// baseline (59.934 us; speedup 1.0000x reference)
//
#include <hip/hip_runtime.h>
#include <hip/hip_bf16.h>
#include <hip/hip_cooperative_groups.h>

namespace cg = cooperative_groups;

#define BATCH   1024
#define IN_DIM  256
#define UNITS   256

using short8 = __attribute__((ext_vector_type(8))) short;
using f32x4  = __attribute__((ext_vector_type(4))) float;

// A_p: [mt=64][s=72][lane=64][e=8] bf16   (M=1024 rows /16, K=2304 /32)
// W_p: [nt=16][s=72][lane=64][e=8] bf16   (N=256 cols /16)
#define A_ELEMS (64 * 72 * 512)   // 2,359,296 ushort
#define W_ELEMS (16 * 72 * 512)   //   589,824 ushort

__device__ __forceinline__ unsigned short f2bf(float v) {
    __hip_bfloat16 h = __float2bfloat16(v);
    return *reinterpret_cast<unsigned short*>(&h);
}

// ================= single cooperative kernel: prep + grid.sync + GEMM ========
__global__ __launch_bounds__(512, 1) void kan_one(
    const float* __restrict__ X, const float* __restrict__ SK,
    const float* __restrict__ SF, const float* __restrict__ BIAS,
    unsigned short* __restrict__ Ap, unsigned short* __restrict__ Wp,
    float* __restrict__ OUT)
{
    __shared__ __align__(16) unsigned char smem[32768];
    const int tid = threadIdx.x;
    const int bid = blockIdx.x;

    // ---------------- phase 1: prep A (tid<256) || prep W (tid>=256) --------
    unsigned short* tile = (unsigned short*)smem;     // 18*512 u16 = 18 KB
    if (tid < 256) {
        const int mt = bid >> 2;
        const int q  = bid & 3;
        #pragma unroll
        for (int rr = 0; rr < 4; ++rr) {
            const int p  = tid + 256 * rr;
            const int b  = p >> 6;          // row in 16-row tile
            const int il = p & 63;          // local i
            const int i  = q * 64 + il;
            const float x = X[(mt * 16 + b) * IN_DIM + i];
            const float u = (x + 2.2f) * 2.5f;
            int j = (int)floorf(u);
            j = j < 3 ? 3 : (j > 7 ? 7 : j);
            const float gj = -2.2f + 0.4f * (float)j;
            const float tt = (x - gj) * 2.5f;
            const float t2 = tt * tt, t3 = t2 * tt;
            const float k6 = 1.f / 6.f;
            const float b0 = (1.f - 3.f * tt + 3.f * t2 - t3) * k6;
            const float b1 = (3.f * t3 - 6.f * t2 + 4.f) * k6;
            const float b2 = (-3.f * t3 + 3.f * t2 + 3.f * tt + 1.f) * k6;
            const float b3 = t3 * k6;
            const float sil = x / (1.f + __expf(-x));
            const int base = j - 3;
            const int kk0  = il * 9;
            #pragma unroll
            for (int kf = 0; kf < 9; ++kf) {
                float v;
                if (kf == 8) v = sil;
                else v = (kf == base)     ? b0
                       : (kf == base + 1) ? b1
                       : (kf == base + 2) ? b2
                       : (kf == base + 3) ? b3 : 0.f;
                const int kkl  = kk0 + kf;
                const int sl   = kkl >> 5;
                const int kpos = kkl & 31;
                tile[sl * 512 + ((b | ((kpos >> 3) << 4)) << 3) + (kpos & 7)] = f2bf(v);
            }
        }
    } else {
        const int base_idx = bid * 256 + (tid - 256);   // 0..65535
        #pragma unroll
        for (int rep = 0; rep < 2; ++rep) {
            const int slot = base_idx + rep * 65536;
            if (slot < 73728) {
                const int lane = slot & 63;
                const int s    = (slot >> 6) % 72;
                const int nt   = slot / (72 * 64);
                const int o    = nt * 16 + (lane & 15);
                const int kb   = (lane >> 4) << 3;
                unsigned short r[8];
                #pragma unroll
                for (int e = 0; e < 8; ++e) {
                    const int kk = s * 32 + kb + e;   // 0..2303
                    const int i  = kk / 9;
                    const int kf = kk - i * 9;
                    const float sfv = SF[i * UNITS + o];
                    const float v = (kf < 8) ? SK[(i * 8 + kf) * UNITS + o] * sfv : sfv;
                    r[e] = f2bf(v);
                }
                unsigned int pk[4];
                #pragma unroll
                for (int e = 0; e < 4; ++e)
                    pk[e] = (unsigned int)r[2 * e] | ((unsigned int)r[2 * e + 1] << 16);
                reinterpret_cast<uint4*>(Wp)[slot] = make_uint4(pk[0], pk[1], pk[2], pk[3]);
            }
        }
    }
    __syncthreads();
    {   // all 512 threads copy the A tile to global (4608 u32)
        const unsigned int* src = (const unsigned int*)tile;
        unsigned int* dst = (unsigned int*)Ap + ((bid >> 2) * 72 + 18 * (bid & 3)) * 256;
        #pragma unroll
        for (int k = 0; k < 9; ++k) dst[tid + 512 * k] = src[tid + 512 * k];
    }

    cg::this_grid().sync();

    // ---------------- phase 2: GEMM (tile 32x32, split-K 8) -----------------
    const int w    = tid >> 6;
    const int lane = tid & 63;
    const int m = bid & 31;
    const int n = bid >> 5;
    const short8* A8 = (const short8*)Ap;
    const short8* W8 = (const short8*)Wp;
    const int mt0 = 2 * m, nt0 = 2 * n;
    const int s0  = 9 * w;

    const short8* pa0 = A8 + (size_t)(mt0 * 72 + s0) * 64 + lane;
    const short8* pa1 = pa0 + 72 * 64;
    const short8* pb0 = W8 + (size_t)(nt0 * 72 + s0) * 64 + lane;
    const short8* pb1 = pb0 + 72 * 64;

    f32x4 acc00 = {0.f, 0.f, 0.f, 0.f}, acc01 = {0.f, 0.f, 0.f, 0.f};
    f32x4 acc10 = {0.f, 0.f, 0.f, 0.f}, acc11 = {0.f, 0.f, 0.f, 0.f};

    short8 a0 = pa0[0], a1 = pa1[0], b0 = pb0[0], b1 = pb1[0];
    #pragma unroll
    for (int it = 0; it < 9; ++it) {
        acc00 = __builtin_amdgcn_mfma_f32_16x16x32_bf16(a0, b0, acc00, 0, 0, 0);
        acc01 = __builtin_amdgcn_mfma_f32_16x16x32_bf16(a0, b1, acc01, 0, 0, 0);
        acc10 = __builtin_amdgcn_mfma_f32_16x16x32_bf16(a1, b0, acc10, 0, 0, 0);
        acc11 = __builtin_amdgcn_mfma_f32_16x16x32_bf16(a1, b1, acc11, 0, 0, 0);
        if (it < 8) {
            a0 = pa0[64 * (it + 1)];
            a1 = pa1[64 * (it + 1)];
            b0 = pb0[64 * (it + 1)];
            b1 = pb1[64 * (it + 1)];
        }
    }

    float* red = (float*)smem;           // 32 KB, reused after grid sync
    f32x4* redv = (f32x4*)red;
    redv[(w * 4 + 0) * 64 + lane] = acc00;
    redv[(w * 4 + 1) * 64 + lane] = acc01;
    redv[(w * 4 + 2) * 64 + lane] = acc10;
    redv[(w * 4 + 3) * 64 + lane] = acc11;
    __syncthreads();

    #pragma unroll
    for (int half = 0; half < 2; ++half) {
        const int flat = half * 512 + tid;
        float sum = 0.f;
        #pragma unroll
        for (int w2 = 0; w2 < 8; ++w2) sum += red[w2 * 1024 + flat];
        const int f  = flat >> 8;
        const int l  = (flat >> 2) & 63;
        const int rr = flat & 3;
        const int row = m * 32 + (f >> 1) * 16 + ((l >> 4) << 2) + rr;
        const int col = n * 32 + (f & 1) * 16 + (l & 15);
        OUT[row * UNITS + col] = sum + BIAS[col];
    }
}

// ================= fallback pair (round-4 verified path) =====================
__global__ __launch_bounds__(256) void prep_all(const float* __restrict__ X,
                                                const float* __restrict__ SK,
                                                const float* __restrict__ SF,
                                                unsigned short* __restrict__ Ap,
                                                unsigned short* __restrict__ Wp) {
    const int t = threadIdx.x;
    if (blockIdx.x < 256) {
        __shared__ unsigned short tile[18 * 512];
        const int mt = blockIdx.x >> 2;
        const int q  = blockIdx.x & 3;
        #pragma unroll
        for (int rr = 0; rr < 4; ++rr) {
            const int p  = t + 256 * rr;
            const int b  = p >> 6;
            const int il = p & 63;
            const int i  = q * 64 + il;
            const float x = X[(mt * 16 + b) * IN_DIM + i];
            const float u = (x + 2.2f) * 2.5f;
            int j = (int)floorf(u);
            j = j < 3 ? 3 : (j > 7 ? 7 : j);
            const float gj = -2.2f + 0.4f * (float)j;
            const float tt = (x - gj) * 2.5f;
            const float t2 = tt * tt, t3 = t2 * tt;
            const float k6 = 1.f / 6.f;
            const float b0 = (1.f - 3.f * tt + 3.f * t2 - t3) * k6;
            const float b1 = (3.f * t3 - 6.f * t2 + 4.f) * k6;
            const float b2 = (-3.f * t3 + 3.f * t2 + 3.f * tt + 1.f) * k6;
            const float b3 = t3 * k6;
            const float sil = x / (1.f + __expf(-x));
            const int base = j - 3;
            const int kk0  = il * 9;
            #pragma unroll
            for (int kf = 0; kf < 9; ++kf) {
                float v;
                if (kf == 8) v = sil;
                else v = (kf == base)     ? b0
                       : (kf == base + 1) ? b1
                       : (kf == base + 2) ? b2
                       : (kf == base + 3) ? b3 : 0.f;
                const int kkl  = kk0 + kf;
                const int sl   = kkl >> 5;
                const int kpos = kkl & 31;
                tile[sl * 512 + ((b | ((kpos >> 3) << 4)) << 3) + (kpos & 7)] = f2bf(v);
            }
        }
        __syncthreads();
        const unsigned int* src = (const unsigned int*)tile;
        unsigned int* dst = (unsigned int*)Ap + (mt * 72 + 18 * q) * 256;
        #pragma unroll
        for (int k = 0; k < 18; ++k) dst[t + 256 * k] = src[t + 256 * k];
    } else {
        const int slot = (blockIdx.x - 256) * 256 + t;
        const int lane = slot & 63;
        const int s    = (slot >> 6) % 72;
        const int nt   = slot / (72 * 64);
        const int o    = nt * 16 + (lane & 15);
        const int kb   = (lane >> 4) << 3;
        unsigned short r[8];
        #pragma unroll
        for (int e = 0; e < 8; ++e) {
            const int kk = s * 32 + kb + e;
            const int i  = kk / 9;
            const int kf = kk - i * 9;
            const float sfv = SF[i * UNITS + o];
            const float v = (kf < 8) ? SK[(i * 8 + kf) * UNITS + o] * sfv : sfv;
            r[e] = f2bf(v);
        }
        unsigned int pack[4];
        #pragma unroll
        for (int e = 0; e < 4; ++e)
            pack[e] = (unsigned int)r[2 * e] | ((unsigned int)r[2 * e + 1] << 16);
        reinterpret_cast<uint4*>(Wp)[slot] = make_uint4(pack[0], pack[1], pack[2], pack[3]);
    }
}

__global__ __launch_bounds__(512) void kan_gemm(const unsigned short* __restrict__ Ap,
                                                const unsigned short* __restrict__ Wp,
                                                const float* __restrict__ BIAS,
                                                float* __restrict__ OUT) {
    __shared__ float red[8 * 1024];
    const int tid  = threadIdx.x;
    const int w    = tid >> 6;
    const int lane = tid & 63;
    const int m = blockIdx.x & 31;
    const int n = blockIdx.x >> 5;
    const short8* A8 = (const short8*)Ap;
    const short8* W8 = (const short8*)Wp;
    const int mt0 = 2 * m, nt0 = 2 * n;
    const int s0  = 9 * w;
    const short8* pa0 = A8 + (size_t)(mt0 * 72 + s0) * 64 + lane;
    const short8* pa1 = pa0 + 72 * 64;
    const short8* pb0 = W8 + (size_t)(nt0 * 72 + s0) * 64 + lane;
    const short8* pb1 = pb0 + 72 * 64;
    f32x4 acc00 = {0.f,0.f,0.f,0.f}, acc01 = {0.f,0.f,0.f,0.f};
    f32x4 acc10 = {0.f,0.f,0.f,0.f}, acc11 = {0.f,0.f,0.f,0.f};
    short8 a0 = pa0[0], a1 = pa1[0], b0 = pb0[0], b1 = pb1[0];
    #pragma unroll
    for (int it = 0; it < 9; ++it) {
        acc00 = __builtin_amdgcn_mfma_f32_16x16x32_bf16(a0, b0, acc00, 0, 0, 0);
        acc01 = __builtin_amdgcn_mfma_f32_16x16x32_bf16(a0, b1, acc01, 0, 0, 0);
        acc10 = __builtin_amdgcn_mfma_f32_16x16x32_bf16(a1, b0, acc10, 0, 0, 0);
        acc11 = __builtin_amdgcn_mfma_f32_16x16x32_bf16(a1, b1, acc11, 0, 0, 0);
        if (it < 8) {
            a0 = pa0[64 * (it + 1)];
            a1 = pa1[64 * (it + 1)];
            b0 = pb0[64 * (it + 1)];
            b1 = pb1[64 * (it + 1)];
        }
    }
    f32x4* redv = (f32x4*)red;
    redv[(w * 4 + 0) * 64 + lane] = acc00;
    redv[(w * 4 + 1) * 64 + lane] = acc01;
    redv[(w * 4 + 2) * 64 + lane] = acc10;
    redv[(w * 4 + 3) * 64 + lane] = acc11;
    __syncthreads();
    #pragma unroll
    for (int half = 0; half < 2; ++half) {
        const int flat = half * 512 + tid;
        float sum = 0.f;
        #pragma unroll
        for (int w2 = 0; w2 < 8; ++w2) sum += red[w2 * 1024 + flat];
        const int f  = flat >> 8;
        const int l  = (flat >> 2) & 63;
        const int rr = flat & 3;
        const int row = m * 32 + (f >> 1) * 16 + ((l >> 4) << 2) + rr;
        const int col = n * 32 + (f & 1) * 16 + (l & 15);
        OUT[row * UNITS + col] = sum + BIAS[col];
    }
}

// ================= fallback (round-1 fused fp32, no workspace) ===============
__global__ __launch_bounds__(256) void kan_fused(
    const float* __restrict__ X, const float* __restrict__ SK,
    const float* __restrict__ SF, const float* __restrict__ BIAS,
    float* __restrict__ OUT) {
    __shared__ float feat[128][12];
    const int tid  = threadIdx.x;
    const int brow = blockIdx.x * 4;
    const int o    = tid;
    float acc[4] = {0.f, 0.f, 0.f, 0.f};
    for (int c = 0; c < 8; ++c) {
        if (tid < 128) {
            const int ii = tid >> 2;
            const int r  = tid & 3;
            const int i  = c * 32 + ii;
            const float x = X[(size_t)(brow + r) * IN_DIM + i];
            float u = (x + 2.2f) * 2.5f;
            int j = (int)floorf(u);
            j = j < 3 ? 3 : (j > 7 ? 7 : j);
            const float gj = -2.2f + 0.4f * (float)j;
            const float t  = (x - gj) * 2.5f;
            const float t2 = t * t, t3 = t2 * t;
            const float k6 = 1.f / 6.f;
            float* fp = feat[ii * 4 + r];
            #pragma unroll
            for (int k = 0; k < 12; ++k) fp[k] = 0.f;
            const int base = j - 3;
            fp[base + 0] = (1.f - 3.f*t + 3.f*t2 - t3) * k6;
            fp[base + 1] = (3.f*t3 - 6.f*t2 + 4.f) * k6;
            fp[base + 2] = (-3.f*t3 + 3.f*t2 + 3.f*t + 1.f) * k6;
            fp[base + 3] = t3 * k6;
            fp[8] = x / (1.f + __expf(-x));
        }
        __syncthreads();
        #pragma unroll 4
        for (int ii = 0; ii < 32; ++ii) {
            const int i = c * 32 + ii;
            const float* skp = SK + (size_t)i * 8 * UNITS + o;
            const float s0 = skp[0*UNITS], s1 = skp[1*UNITS], s2 = skp[2*UNITS], s3 = skp[3*UNITS];
            const float s4 = skp[4*UNITS], s5 = skp[5*UNITS], s6 = skp[6*UNITS], s7 = skp[7*UNITS];
            const float sfv = SF[(size_t)i * UNITS + o];
            #pragma unroll
            for (int r = 0; r < 4; ++r) {
                const float* fp = feat[ii * 4 + r];
                const float4 fa = *(const float4*)(fp);
                const float4 fb = *(const float4*)(fp + 4);
                float ts = fp[8];
                ts = fmaf(fa.x, s0, ts); ts = fmaf(fa.y, s1, ts);
                ts = fmaf(fa.z, s2, ts); ts = fmaf(fa.w, s3, ts);
                ts = fmaf(fb.x, s4, ts); ts = fmaf(fb.y, s5, ts);
                ts = fmaf(fb.z, s6, ts); ts = fmaf(fb.w, s7, ts);
                acc[r] = fmaf(sfv, ts, acc[r]);
            }
        }
        __syncthreads();
    }
    const float bo = BIAS[o];
    #pragma unroll
    for (int r = 0; r < 4; ++r)
        OUT[(size_t)(brow + r) * UNITS + o] = acc[r] + bo;
}

extern "C" void kernel_launch(void* const* d_in, const int* in_sizes, int n_in,
                              void* d_out, int out_size, void* d_ws, size_t ws_size,
                              hipStream_t stream) {
    const float* X  = (const float*)d_in[0];
    const float* SK = (const float*)d_in[1];
    const float* SF = (const float*)d_in[2];
    const float* B  = (const float*)d_in[3];
    float* OUT = (float*)d_out;

    const size_t need = ((size_t)A_ELEMS + (size_t)W_ELEMS) * 2;   // 5,898,240 B
    if (d_ws != nullptr && ws_size >= need) {
        unsigned short* Ap = (unsigned short*)d_ws;
        unsigned short* Wp = Ap + A_ELEMS;
        void* args[] = { (void*)&X, (void*)&SK, (void*)&SF, (void*)&B,
                         (void*)&Ap, (void*)&Wp, (void*)&OUT };
        hipError_t e = hipLaunchCooperativeKernel((const void*)kan_one,
                                                  dim3(256), dim3(512),
                                                  args, 0, stream);
        if (e != hipSuccess) {
            prep_all<<<dim3(544), dim3(256), 0, stream>>>(X, SK, SF, Ap, Wp);
            kan_gemm<<<dim3(256), dim3(512), 0, stream>>>(Ap, Wp, B, OUT);
        }
    } else {
        kan_fused<<<dim3(BATCH / 4), dim3(256), 0, stream>>>(X, SK, SF, B, OUT);
    }
}

// Round 6
// 19.738 us; speedup vs baseline: 3.0364x; 3.0364x over previous
//
#include <hip/hip_runtime.h>
#include <hip/hip_bf16.h>

#define BATCH   1024
#define IN_DIM  256
#define UNITS   256

using short8 = __attribute__((ext_vector_type(8))) short;
using f32x4  = __attribute__((ext_vector_type(4))) float;
using u32x4  = __attribute__((ext_vector_type(4))) unsigned int;

__device__ __forceinline__ unsigned short f2bf(float v) {
    __hip_bfloat16 h = __float2bfloat16(v);
    return *reinterpret_cast<unsigned short*>(&h);
}

// 8 padded features kf=0..7 of x (cubic B-spline bases on uniform grid,
// 4 nonzero at offset base=j-3 in 0..4), packed bf16 into a short8 via
// a guarded 128-bit funnel shift.
__device__ __forceinline__ short8 bases_frag(float x) {
    const float u = fmaf(x, 2.5f, 5.5f);           // (x + 2.2) * 2.5
    float fj = floorf(u);
    fj = fj < 3.f ? 3.f : (fj > 7.f ? 7.f : fj);
    const float t  = u - fj;                        // == (x - g_j) * 2.5
    const float s1 = 1.f - t;
    const float t2 = t * t;
    const float t3 = t2 * t;
    const float b0 = s1 * s1 * s1 * (1.f / 6.f);
    const float b1 = fmaf(0.5f, t3, fmaf(-1.f, t2, 2.f / 3.f));
    const float b3 = t3 * (1.f / 6.f);
    const float b2 = 1.f - b0 - b1 - b3;            // partition of unity
    const unsigned int p01 = (unsigned int)f2bf(b0) | ((unsigned int)f2bf(b1) << 16);
    const unsigned int p23 = (unsigned int)f2bf(b2) | ((unsigned int)f2bf(b3) << 16);
    const unsigned long long A = (unsigned long long)p01 | ((unsigned long long)p23 << 32);
    const int base = (int)fj - 3;                   // 0..4
    const int sh   = base << 4;                     // 0,16,32,48,64
    const unsigned long long lo = (sh < 64) ? (A << (sh & 63)) : 0ULL;
    const unsigned long long hi = (sh == 0) ? 0ULL
                                : ((sh >= 64) ? A : (A >> ((64 - sh) & 63)));
    u32x4 r;
    r.x = (unsigned int)lo;  r.y = (unsigned int)(lo >> 32);
    r.z = (unsigned int)hi;  r.w = (unsigned int)(hi >> 32);
    return __builtin_bit_cast(short8, r);
}

// features kf=8..15: [silu(x), 0,0,0,0,0,0,0]
__device__ __forceinline__ short8 silu_frag(float x) {
    const float sil = x / (1.f + __expf(-x));
    u32x4 r; r.x = (unsigned int)f2bf(sil); r.y = 0u; r.z = 0u; r.w = 0u;
    return __builtin_bit_cast(short8, r);
}

// ============ single dispatch: 256 blocks x 512 thr, tile 32x32, split-K-8 ===
// K = 4096 (16 padded features per i). Wave w owns k in [512w, 512w+512):
// 16 K-steps, i-pair (32w+2s, 32w+2s+1) per step. Lane role (fixed):
//   l15 = lane&15 : A-row / B-col within 16-group
//   g = lane>>4; gi = g>>1 selects i of the pair; par = g&1 selects
//   kf-half: par==0 -> bases / sk*sf ; par==1 -> silu / sf.
__global__ __launch_bounds__(512, 1) void kan_mono(
    const float* __restrict__ X, const float* __restrict__ SK,
    const float* __restrict__ SF, const float* __restrict__ BIAS,
    float* __restrict__ OUT)
{
    __shared__ __align__(16) float smem[8 * 32 * 36];   // 36 KB; X-stage, then reduce
    const int tid  = threadIdx.x;
    const int w    = tid >> 6;
    const int lane = tid & 63;
    const int m = blockIdx.x & 31;
    const int n = blockIdx.x >> 5;
    const int l15 = lane & 15;
    const int g   = lane >> 4;
    const int gi  = g >> 1;
    const int par = g & 1;

    // ---- stage X tile (rows m*32..+32, i in [32w, 32w+32)) wave-locally ----
    #pragma unroll
    for (int q = 0; q < 4; ++q) {
        const int flat = q * 64 + lane;
        const int row  = flat >> 3;
        const int seg  = flat & 7;
        const float4 v = *(const float4*)(X + (m * 32 + row) * IN_DIM + w * 32 + seg * 4);
        *(float4*)(smem + w * 1152 + row * 36 + seg * 4) = v;
    }
    // no block barrier: each wave reads only its own region (in-order DS)

    const int o0    = n * 32 + l15;
    const int o1    = o0 + 16;
    const int ibase = w * 32 + gi;

    f32x4 acc00 = {0,0,0,0}, acc01 = {0,0,0,0};
    f32x4 acc10 = {0,0,0,0}, acc11 = {0,0,0,0};
    const float* xb = smem + w * 1152 + l15 * 36 + gi;

    #pragma unroll
    for (int s = 0; s < 16; ++s) {
        const int i = ibase + 2 * s;
        const float x0  = xb[2 * s];          // row l15
        const float x1  = xb[2 * s + 576];    // row l15 + 16
        const float sf0 = SF[i * UNITS + o0];
        const float sf1 = SF[i * UNITS + o1];
        short8 a0, a1, b0, b1;
        if (par == 0) {
            a0 = bases_frag(x0);
            a1 = bases_frag(x1);
            const float* skp = SK + (size_t)i * 8 * UNITS;
            unsigned int q0[4], q1[4];
            #pragma unroll
            for (int e2 = 0; e2 < 4; ++e2) {
                const float v00 = skp[(2 * e2    ) * UNITS + o0] * sf0;
                const float v01 = skp[(2 * e2 + 1) * UNITS + o0] * sf0;
                const float v10 = skp[(2 * e2    ) * UNITS + o1] * sf1;
                const float v11 = skp[(2 * e2 + 1) * UNITS + o1] * sf1;
                q0[e2] = (unsigned int)f2bf(v00) | ((unsigned int)f2bf(v01) << 16);
                q1[e2] = (unsigned int)f2bf(v10) | ((unsigned int)f2bf(v11) << 16);
            }
            u32x4 t0 = {q0[0], q0[1], q0[2], q0[3]};
            u32x4 t1 = {q1[0], q1[1], q1[2], q1[3]};
            b0 = __builtin_bit_cast(short8, t0);
            b1 = __builtin_bit_cast(short8, t1);
        } else {
            a0 = silu_frag(x0);
            a1 = silu_frag(x1);
            u32x4 t0 = {(unsigned int)f2bf(sf0), 0u, 0u, 0u};
            u32x4 t1 = {(unsigned int)f2bf(sf1), 0u, 0u, 0u};
            b0 = __builtin_bit_cast(short8, t0);
            b1 = __builtin_bit_cast(short8, t1);
        }
        acc00 = __builtin_amdgcn_mfma_f32_16x16x32_bf16(a0, b0, acc00, 0, 0, 0);
        acc01 = __builtin_amdgcn_mfma_f32_16x16x32_bf16(a0, b1, acc01, 0, 0, 0);
        acc10 = __builtin_amdgcn_mfma_f32_16x16x32_bf16(a1, b0, acc10, 0, 0, 0);
        acc11 = __builtin_amdgcn_mfma_f32_16x16x32_bf16(a1, b1, acc11, 0, 0, 0);
    }

    // ---- split-K reduce (verified R4 epilogue) ----
    __syncthreads();                      // all waves done reading X regions
    f32x4* redv = (f32x4*)smem;
    redv[(w * 4 + 0) * 64 + lane] = acc00;
    redv[(w * 4 + 1) * 64 + lane] = acc01;
    redv[(w * 4 + 2) * 64 + lane] = acc10;
    redv[(w * 4 + 3) * 64 + lane] = acc11;
    __syncthreads();
    const float* red = (const float*)smem;
    #pragma unroll
    for (int half = 0; half < 2; ++half) {
        const int flat = half * 512 + tid;
        float sum = 0.f;
        #pragma unroll
        for (int w2 = 0; w2 < 8; ++w2) sum += red[w2 * 1024 + flat];
        const int f  = flat >> 8;
        const int l  = (flat >> 2) & 63;
        const int rr = flat & 3;
        const int row = m * 32 + (f >> 1) * 16 + ((l >> 4) << 2) + rr;
        const int col = n * 32 + (f & 1) * 16 + (l & 15);
        OUT[row * UNITS + col] = sum + BIAS[col];
    }
}

extern "C" void kernel_launch(void* const* d_in, const int* in_sizes, int n_in,
                              void* d_out, int out_size, void* d_ws, size_t ws_size,
                              hipStream_t stream) {
    const float* X  = (const float*)d_in[0];
    const float* SK = (const float*)d_in[1];
    const float* SF = (const float*)d_in[2];
    const float* B  = (const float*)d_in[3];
    float* OUT = (float*)d_out;
    kan_mono<<<dim3(256), dim3(512), 0, stream>>>(X, SK, SF, B, OUT);
}